// Round 3
// baseline (220.218 us; speedup 1.0000x reference)
//
#include <hip/hip_runtime.h>
#include <stdint.h>

#define NN 4096
#define FF 256
#define HH 4
#define DD 64
#define NEG 0.2f

#define ITILE 16
#define NSLICE 8
#define JRANGE (NN / NSLICE)   // 512

typedef __attribute__((ext_vector_type(8))) short short8;
typedef __attribute__((ext_vector_type(4))) float f32x4;

__device__ __forceinline__ uint16_t bf16_rh(float f) {
    uint32_t u = __float_as_uint(f);
    return (uint16_t)((u + 0x8000u) >> 16);
}
__device__ __forceinline__ uint32_t enc_key(float f) {
    uint32_t u = __float_as_uint(f);
    return (u & 0x80000000u) ? ~u : (u | 0x80000000u);
}
__device__ __forceinline__ float dec_key(uint32_t k) {
    uint32_t u = (k & 0x80000000u) ? (k & 0x7fffffffu) : ~k;
    return __uint_as_float(u);
}

// ---------------- convert x, W to bf16 --------------------------------------
__global__ __launch_bounds__(256) void cvt_inputs(const float* __restrict__ x,
                                                  const float* __restrict__ W,
                                                  uint16_t* __restrict__ xb,
                                                  uint16_t* __restrict__ Wb) {
    const int idx = blockIdx.x * 256 + threadIdx.x;  // float4 index
    const int nx = NN * FF / 4;
    const int nw = FF * FF / 4;
    if (idx < nx) {
        float4 v = ((const float4*)x)[idx];
        ushort4 o;
        o.x = bf16_rh(v.x); o.y = bf16_rh(v.y);
        o.z = bf16_rh(v.z); o.w = bf16_rh(v.w);
        ((ushort4*)xb)[idx] = o;
    } else if (idx < nx + nw) {
        int k = idx - nx;
        float4 v = ((const float4*)W)[k];
        ushort4 o;
        o.x = bf16_rh(v.x); o.y = bf16_rh(v.y);
        o.z = bf16_rh(v.z); o.w = bf16_rh(v.w);
        ((ushort4*)Wb)[k] = o;
    }
}

// ---------------- fused: h=x@W^T (MFMA) + s,t + H_T transpose + gmax --------
// 256 blocks x 16 nodes; wave w == head w (f-range [w*64,(w+1)*64)).
// Barrier-free: frags direct from global; s/t via in-wave shuffle reduction
// over the accumulator; H_T written bf16 straight from acc regs.
__global__ __launch_bounds__(256) void proj_fused(
    const uint16_t* __restrict__ xb, const uint16_t* __restrict__ Wb,
    const float* __restrict__ a_src, const float* __restrict__ a_dst,
    uint16_t* __restrict__ H_T, float* __restrict__ s,
    float* __restrict__ T_T, uint32_t* __restrict__ gkey) {
    const int tid = threadIdx.x;
    const int w = tid >> 6, l = tid & 63;
    const int m = l & 15, q = l >> 4;           // C: col=m, row=q*4+reg
    const int i0 = blockIdx.x * ITILE;
    f32x4 acc[4];
#pragma unroll
    for (int n = 0; n < 4; n++)
#pragma unroll
        for (int r = 0; r < 4; r++) acc[n][r] = 0.f;
    const uint16_t* arow = xb + (size_t)(i0 + m) * FF + q * 8;
    const uint16_t* brow = Wb + (size_t)(w * 64 + m) * FF + q * 8;
#pragma unroll
    for (int k0 = 0; k0 < FF; k0 += 32) {
        short8 af = *(const short8*)(arow + k0);
#pragma unroll
        for (int n = 0; n < 4; n++) {
            short8 bf = *(const short8*)(brow + (size_t)n * 16 * FF + k0);
            acc[n] = __builtin_amdgcn_mfma_f32_16x16x32_bf16(af, bf, acc[n], 0, 0, 0);
        }
    }
    // H_T[f][i]: lane's f = w*64+n*16+m, i = i0+q*4+r  -> one 8B write per n
#pragma unroll
    for (int n = 0; n < 4; n++) {
        ushort4 o;
        o.x = bf16_rh(acc[n][0]); o.y = bf16_rh(acc[n][1]);
        o.z = bf16_rh(acc[n][2]); o.w = bf16_rh(acc[n][3]);
        *(ushort4*)(H_T + (size_t)(w * 64 + n * 16 + m) * NN + i0 + q * 4) = o;
    }
    // s,t: reduce over f (i.e. over n and lanes m) for this wave's head
    float ps[4] = {0.f, 0.f, 0.f, 0.f}, pt[4] = {0.f, 0.f, 0.f, 0.f};
#pragma unroll
    for (int n = 0; n < 4; n++) {
        float av = a_src[w * 64 + n * 16 + m];
        float dv = a_dst[w * 64 + n * 16 + m];
#pragma unroll
        for (int r = 0; r < 4; r++) {
            ps[r] = fmaf(acc[n][r], av, ps[r]);
            pt[r] = fmaf(acc[n][r], dv, pt[r]);
        }
    }
#pragma unroll
    for (int off = 1; off < 16; off <<= 1) {
#pragma unroll
        for (int r = 0; r < 4; r++) {
            ps[r] += __shfl_xor(ps[r], off, 64);
            pt[r] += __shfl_xor(pt[r], off, 64);
        }
    }
    if (m < 4) {                                // lane m writes reg r=m
        int i = i0 + q * 4 + m;
        s[(size_t)i * HH + w] = ps[m];
        T_T[(size_t)w * NN + i] = pt[m];
    }
    float tm = fmaxf(fmaxf(pt[0], pt[1]), fmaxf(pt[2], pt[3]));
    tm = fmaxf(tm, __shfl_xor(tm, 16, 64));
    tm = fmaxf(tm, __shfl_xor(tm, 32, 64));
    if (l == 0) atomicMax(&gkey[w], enc_key(tm));
}

// ---------------- fused scores -> exp -> P (A-frag regs) -> MFMA PV ---------
// 16 i x 512 j per block; wave w = head w; NO LDS, NO barriers — adj/t/B
// frags straight from global (L1/L2-hot); bf16 slice partials to ws.
__global__ __launch_bounds__(256, 6) void gat_main(
    const float* __restrict__ adj, const uint16_t* __restrict__ H_T,
    const float* __restrict__ s, const float* __restrict__ T_T,
    const uint32_t* __restrict__ gkey, float* __restrict__ pden,
    uint16_t* __restrict__ part) {
    const int tid = threadIdx.x;
    const int w = tid >> 6, l = tid & 63;
    const int m = l & 15, q = l >> 4;           // A: row=m, k=q*8+j
    const int i0 = blockIdx.x * ITILE;
    const int jb = blockIdx.y * JRANGE;

    const float gm = dec_key(gkey[w]);
    const float sS = s[(size_t)(i0 + m) * HH + w];
    const float xM = sS + gm;
    const float ML = fmaxf(xM, NEG * xM);       // lrelu monotone upper bound
    float den = 0.f;
    f32x4 acc[4];
#pragma unroll
    for (int n = 0; n < 4; n++)
#pragma unroll
        for (int r = 0; r < 4; r++) acc[n][r] = 0.f;
    const float* arow = adj + (size_t)(i0 + m) * NN;
    const float* trow = T_T + (size_t)w * NN;
    const uint16_t* brow = H_T + (size_t)(w * 64 + m) * NN;

    for (int jc = jb; jc < jb + JRANGE; jc += 32) {
        const int jg = jc + q * 8;              // this lane's 8 j's
        float4 a0 = *(const float4*)(arow + jg);
        float4 a1 = *(const float4*)(arow + jg + 4);
        float4 t0 = *(const float4*)(trow + jg);
        float4 t1 = *(const float4*)(trow + jg + 4);
        float av[8] = {a0.x, a0.y, a0.z, a0.w, a1.x, a1.y, a1.z, a1.w};
        float tt[8] = {t0.x, t0.y, t0.z, t0.w, t1.x, t1.y, t1.z, t1.w};
        uint32_t pk[4];
#pragma unroll
        for (int jj = 0; jj < 8; jj += 2) {
            float x0 = sS + tt[jj], x1 = sS + tt[jj + 1];
            float lr0 = fmaxf(x0, NEG * x0), lr1 = fmaxf(x1, NEG * x1);
            float e0 = __expf(lr0 - ML), e1 = __expf(lr1 - ML);
            e0 = (av[jj] > 0.f) ? e0 : 0.f;
            e1 = (av[jj + 1] > 0.f) ? e1 : 0.f;
            den += e0 + e1;
            float p0 = e0 * av[jj], p1 = e1 * av[jj + 1];
            uint32_t u0 = __float_as_uint(p0) + 0x8000u;
            uint32_t u1 = __float_as_uint(p1) + 0x8000u;
            pk[jj >> 1] = (u0 >> 16) | (u1 & 0xffff0000u);
        }
        union { uint32_t u[4]; short8 v; } afu;
#pragma unroll
        for (int c = 0; c < 4; c++) afu.u[c] = pk[c];
#pragma unroll
        for (int n = 0; n < 4; n++) {
            short8 bf = *(const short8*)(brow + (size_t)n * 16 * NN + jg);
            acc[n] = __builtin_amdgcn_mfma_f32_16x16x32_bf16(afu.v, bf, acc[n], 0, 0, 0);
        }
    }
    den += __shfl_xor(den, 16, 64);             // reduce over q
    den += __shfl_xor(den, 32, 64);
    if (l < 16) atomicAdd(&pden[(size_t)(i0 + m) * HH + w], den);
    uint16_t* pbase = part + (size_t)blockIdx.y * NN * FF;
#pragma unroll
    for (int n = 0; n < 4; n++)
#pragma unroll
        for (int r = 0; r < 4; r++)
            pbase[(size_t)(i0 + q * 4 + r) * FF + w * 64 + n * 16 + m] =
                bf16_rh(acc[n][r]);
}

// ---------------- sum slice partials, divide by denom -----------------------
__global__ __launch_bounds__(256) void finalize(const uint16_t* __restrict__ part,
                                                const float* __restrict__ pden,
                                                float* __restrict__ out) {
    const int i = blockIdx.x, f = threadIdx.x;
    float sum = 0.f;
#pragma unroll
    for (int sl = 0; sl < NSLICE; sl++) {
        uint16_t v = part[(size_t)sl * NN * FF + (size_t)i * FF + f];
        sum += __uint_as_float(((uint32_t)v) << 16);
    }
    float d = pden[(size_t)i * HH + (f >> 6)];
    out[(size_t)i * FF + f] = (d > 0.f) ? sum / d : 0.f;
}

extern "C" void kernel_launch(void* const* d_in, const int* in_sizes, int n_in,
                              void* d_out, int out_size, void* d_ws, size_t ws_size,
                              hipStream_t stream) {
    const float* x     = (const float*)d_in[0];
    const float* adj   = (const float*)d_in[1];
    const float* W     = (const float*)d_in[2];
    const float* a_src = (const float*)d_in[3];
    const float* a_dst = (const float*)d_in[4];
    float* out = (float*)d_out;

    char* ws = (char*)d_ws;
    uint16_t* xb   = (uint16_t*)ws;                        // 2 MB
    uint16_t* Wb   = (uint16_t*)(ws + (2u << 20));         // 128 KB
    uint16_t* H_T  = (uint16_t*)(ws + (4u << 20));         // 2 MB
    uint16_t* part = (uint16_t*)(ws + (8u << 20));         // 16 MB
    float*    s    = (float*)(ws + (24u << 20));           // 64 KB
    float*    T_T  = s + (size_t)NN * HH;                  // 64 KB
    float*    pden = T_T + (size_t)NN * HH;                // 64 KB
    uint32_t* gkey = (uint32_t*)(pden + (size_t)NN * HH);  // 16 B

    hipMemsetAsync(pden, 0, (size_t)NN * HH * sizeof(float) + 16, stream);
    cvt_inputs<<<(NN * FF / 4 + FF * FF / 4 + 255) / 256, 256, 0, stream>>>(x, W, xb, Wb);
    proj_fused<<<NN / ITILE, 256, 0, stream>>>(xb, Wb, a_src, a_dst, H_T, s, T_T, gkey);
    gat_main<<<dim3(NN / ITILE, NSLICE), 256, 0, stream>>>(adj, H_T, s, T_T, gkey, pden, part);
    finalize<<<NN, 256, 0, stream>>>(part, pden, out);
}

// Round 4
// 207.883 us; speedup vs baseline: 1.0593x; 1.0593x over previous
//
#include <hip/hip_runtime.h>
#include <stdint.h>

#define NN 4096
#define FF 256
#define HH 4
#define DD 64
#define NEG 0.2f

#define ITILE 16
#define NSLICE 8
#define JRANGE (NN / NSLICE)   // 512
#define CJ 64
#define NST (JRANGE / CJ)      // 8

typedef __attribute__((ext_vector_type(8))) short short8;
typedef __attribute__((ext_vector_type(4))) float f32x4;

#if __has_builtin(__builtin_amdgcn_exp2f)
#define EXP2F(x) __builtin_amdgcn_exp2f(x)
#else
#define EXP2F(x) exp2f(x)
#endif
#define LOG2E 1.4426950408889634f

__device__ __forceinline__ uint16_t bf16_rh(float f) {
    uint32_t u = __float_as_uint(f);
    return (uint16_t)((u + 0x8000u) >> 16);
}
__device__ __forceinline__ uint32_t enc_key(float f) {
    uint32_t u = __float_as_uint(f);
    return (u & 0x80000000u) ? ~u : (u | 0x80000000u);
}
__device__ __forceinline__ float dec_key(uint32_t k) {
    uint32_t u = (k & 0x80000000u) ? (k & 0x7fffffffu) : ~k;
    return __uint_as_float(u);
}

// ---------------- convert x, W to bf16 --------------------------------------
__global__ __launch_bounds__(256) void cvt_inputs(const float* __restrict__ x,
                                                  const float* __restrict__ W,
                                                  uint16_t* __restrict__ xb,
                                                  uint16_t* __restrict__ Wb) {
    const int idx = blockIdx.x * 256 + threadIdx.x;  // float4 index
    const int nx = NN * FF / 4;
    const int nw = FF * FF / 4;
    if (idx < nx) {
        float4 v = ((const float4*)x)[idx];
        ushort4 o;
        o.x = bf16_rh(v.x); o.y = bf16_rh(v.y);
        o.z = bf16_rh(v.z); o.w = bf16_rh(v.w);
        ((ushort4*)xb)[idx] = o;
    } else if (idx < nx + nw) {
        int k = idx - nx;
        float4 v = ((const float4*)W)[k];
        ushort4 o;
        o.x = bf16_rh(v.x); o.y = bf16_rh(v.y);
        o.z = bf16_rh(v.z); o.w = bf16_rh(v.w);
        ((ushort4*)Wb)[k] = o;
    }
}

// ---------------- fused: h=x@W^T (MFMA) + s,t + H_T transpose + gmax --------
__global__ __launch_bounds__(256) void proj_fused(
    const uint16_t* __restrict__ xb, const uint16_t* __restrict__ Wb,
    const float* __restrict__ a_src, const float* __restrict__ a_dst,
    uint16_t* __restrict__ H_T, float* __restrict__ s,
    float* __restrict__ T_T, uint32_t* __restrict__ gkey) {
    const int tid = threadIdx.x;
    const int w = tid >> 6, l = tid & 63;
    const int m = l & 15, q = l >> 4;           // C: col=m, row=q*4+reg
    const int i0 = blockIdx.x * ITILE;
    f32x4 acc[4];
#pragma unroll
    for (int n = 0; n < 4; n++)
#pragma unroll
        for (int r = 0; r < 4; r++) acc[n][r] = 0.f;
    const uint16_t* arow = xb + (size_t)(i0 + m) * FF + q * 8;
    const uint16_t* brow = Wb + (size_t)(w * 64 + m) * FF + q * 8;
#pragma unroll
    for (int k0 = 0; k0 < FF; k0 += 32) {
        short8 af = *(const short8*)(arow + k0);
#pragma unroll
        for (int n = 0; n < 4; n++) {
            short8 bf = *(const short8*)(brow + (size_t)n * 16 * FF + k0);
            acc[n] = __builtin_amdgcn_mfma_f32_16x16x32_bf16(af, bf, acc[n], 0, 0, 0);
        }
    }
#pragma unroll
    for (int n = 0; n < 4; n++) {
        ushort4 o;
        o.x = bf16_rh(acc[n][0]); o.y = bf16_rh(acc[n][1]);
        o.z = bf16_rh(acc[n][2]); o.w = bf16_rh(acc[n][3]);
        *(ushort4*)(H_T + (size_t)(w * 64 + n * 16 + m) * NN + i0 + q * 4) = o;
    }
    float ps[4] = {0.f, 0.f, 0.f, 0.f}, pt[4] = {0.f, 0.f, 0.f, 0.f};
#pragma unroll
    for (int n = 0; n < 4; n++) {
        float av = a_src[w * 64 + n * 16 + m];
        float dv = a_dst[w * 64 + n * 16 + m];
#pragma unroll
        for (int r = 0; r < 4; r++) {
            ps[r] = fmaf(acc[n][r], av, ps[r]);
            pt[r] = fmaf(acc[n][r], dv, pt[r]);
        }
    }
#pragma unroll
    for (int off = 1; off < 16; off <<= 1) {
#pragma unroll
        for (int r = 0; r < 4; r++) {
            ps[r] += __shfl_xor(ps[r], off, 64);
            pt[r] += __shfl_xor(pt[r], off, 64);
        }
    }
    if (m < 4) {
        int i = i0 + q * 4 + m;
        s[(size_t)i * HH + w] = ps[m];
        T_T[(size_t)w * NN + i] = pt[m];
    }
    float tm = fmaxf(fmaxf(pt[0], pt[1]), fmaxf(pt[2], pt[3]));
    tm = fmaxf(tm, __shfl_xor(tm, 16, 64));
    tm = fmaxf(tm, __shfl_xor(tm, 32, 64));
    if (l == 0) atomicMax(&gkey[w], enc_key(tm));
}

// ---------------- fused scores -> exp -> P (A-frag regs) -> MFMA PV ---------
// 16 i x 512 j per block; wave w = head w. adj staged coalesced via
// global_load_lds into unpadded [16][64] with XOR block-swizzle
// (pos = jblk ^ (row&3)) so DMA writes and ds_read_b128 are bank-uniform.
// Double-buffered: ONE barrier per 64-j stage, prefetch in flight across it.
__global__ __launch_bounds__(256, 8) void gat_main(
    const float* __restrict__ adj, const uint16_t* __restrict__ H_T,
    const float* __restrict__ s, const float* __restrict__ T_T,
    const uint32_t* __restrict__ gkey, float* __restrict__ pden,
    uint16_t* __restrict__ part) {
    __shared__ __align__(16) float adj_s[2][16][64];   // 8 KB
    const int tid = threadIdx.x;
    const int w = tid >> 6, l = tid & 63;
    const int m = l & 15, q = l >> 4;           // A: row=m, k=q*8+j
    const int i0 = blockIdx.x * ITILE;
    const int jb = blockIdx.y * JRANGE;

    // staging map: thread -> (row is, swizzled global j-block)
    const int is_st = tid >> 4;
    const int b_st = (tid & 15) ^ (is_st & 3);
    const float* gsrc = adj + (size_t)(i0 + is_st) * NN + jb + b_st * 4;
    char* ldst = (char*)&adj_s[0][w * 4][0];    // wave-uniform; HW adds lane*16

    const float gm = dec_key(gkey[w]);
    const float sS = s[(size_t)(i0 + m) * HH + w];
    const float xM = sS + gm;
    const float ML = fmaxf(xM, NEG * xM);       // lrelu monotone upper bound
    const float nMLL = -ML * LOG2E;
    float den = 0.f;
    f32x4 acc[4];
#pragma unroll
    for (int n = 0; n < 4; n++)
#pragma unroll
        for (int r = 0; r < 4; r++) acc[n][r] = 0.f;
    const float* trow = T_T + (size_t)w * NN;
    const uint16_t* brow = H_T + (size_t)(w * 64 + m) * NN;
    // reader swizzle: window0 blocks {2q, 2q+1}; window1 = +8 positions
    const int p00 = (2 * q) ^ (m & 3);
    const int p01 = (2 * q + 1) ^ (m & 3);
    const float* lbase = (const float*)adj_s + (size_t)m * 64;

    __builtin_amdgcn_global_load_lds(
        (const __attribute__((address_space(1))) void*)gsrc,
        (__attribute__((address_space(3))) void*)ldst, 16, 0, 0);

    int buf = 0;
    for (int st = 0; st < NST; st++) {
        __syncthreads();                         // stage(st) writes visible
        if (st + 1 < NST)
            __builtin_amdgcn_global_load_lds(
                (const __attribute__((address_space(1))) void*)(gsrc + (st + 1) * CJ),
                (__attribute__((address_space(3))) void*)(ldst + ((buf ^ 1) * 4096)),
                16, 0, 0);
        const float* lb = lbase + buf * 1024;    // this buffer, row m
        const int jc = jb + st * CJ;
#pragma unroll
        for (int win = 0; win < 2; win++) {
            const int jg = jc + win * 32 + q * 8;
            float4 a0 = *(const float4*)(lb + p00 * 4 + win * 32);
            float4 a1 = *(const float4*)(lb + p01 * 4 + win * 32);
            float4 t0 = *(const float4*)(trow + jg);
            float4 t1 = *(const float4*)(trow + jg + 4);
            float av[8] = {a0.x, a0.y, a0.z, a0.w, a1.x, a1.y, a1.z, a1.w};
            float tt[8] = {t0.x, t0.y, t0.z, t0.w, t1.x, t1.y, t1.z, t1.w};
            uint32_t pk[4];
#pragma unroll
            for (int jj = 0; jj < 8; jj += 2) {
                float x0 = sS + tt[jj], x1 = sS + tt[jj + 1];
                float lr0 = fmaxf(x0, NEG * x0), lr1 = fmaxf(x1, NEG * x1);
                float e0 = EXP2F(fmaf(lr0, LOG2E, nMLL));
                float e1 = EXP2F(fmaf(lr1, LOG2E, nMLL));
                e0 = (av[jj] > 0.f) ? e0 : 0.f;
                e1 = (av[jj + 1] > 0.f) ? e1 : 0.f;
                den += e0 + e1;
                uint32_t u0 = __float_as_uint(e0 * av[jj]) + 0x8000u;
                uint32_t u1 = __float_as_uint(e1 * av[jj + 1]) + 0x8000u;
                pk[jj >> 1] = (u0 >> 16) | (u1 & 0xffff0000u);
            }
            union { uint32_t u[4]; short8 v; } afu;
#pragma unroll
            for (int c = 0; c < 4; c++) afu.u[c] = pk[c];
#pragma unroll
            for (int n = 0; n < 4; n++) {
                short8 bf = *(const short8*)(brow + (size_t)n * 16 * NN + jg);
                acc[n] = __builtin_amdgcn_mfma_f32_16x16x32_bf16(afu.v, bf, acc[n], 0, 0, 0);
            }
        }
        buf ^= 1;
    }
    den += __shfl_xor(den, 16, 64);
    den += __shfl_xor(den, 32, 64);
    if (l < 16) atomicAdd(&pden[(size_t)(i0 + m) * HH + w], den);
    uint16_t* pbase = part + (size_t)blockIdx.y * NN * FF;
#pragma unroll
    for (int n = 0; n < 4; n++)
#pragma unroll
        for (int r = 0; r < 4; r++)
            pbase[(size_t)(i0 + q * 4 + r) * FF + w * 64 + n * 16 + m] =
                bf16_rh(acc[n][r]);
}

// ---------------- sum slice partials, divide by denom -----------------------
__global__ __launch_bounds__(256) void finalize(const uint16_t* __restrict__ part,
                                                const float* __restrict__ pden,
                                                float* __restrict__ out) {
    const int i = blockIdx.x, f = threadIdx.x;
    float sum = 0.f;
#pragma unroll
    for (int sl = 0; sl < NSLICE; sl++) {
        uint16_t v = part[(size_t)sl * NN * FF + (size_t)i * FF + f];
        sum += __uint_as_float(((uint32_t)v) << 16);
    }
    float d = pden[(size_t)i * HH + (f >> 6)];
    out[(size_t)i * FF + f] = (d > 0.f) ? sum / d : 0.f;
}

extern "C" void kernel_launch(void* const* d_in, const int* in_sizes, int n_in,
                              void* d_out, int out_size, void* d_ws, size_t ws_size,
                              hipStream_t stream) {
    const float* x     = (const float*)d_in[0];
    const float* adj   = (const float*)d_in[1];
    const float* W     = (const float*)d_in[2];
    const float* a_src = (const float*)d_in[3];
    const float* a_dst = (const float*)d_in[4];
    float* out = (float*)d_out;

    char* ws = (char*)d_ws;
    uint16_t* xb   = (uint16_t*)ws;                        // 2 MB
    uint16_t* Wb   = (uint16_t*)(ws + (2u << 20));         // 128 KB
    uint16_t* H_T  = (uint16_t*)(ws + (4u << 20));         // 2 MB
    uint16_t* part = (uint16_t*)(ws + (8u << 20));         // 16 MB
    float*    s    = (float*)(ws + (24u << 20));           // 64 KB
    float*    T_T  = s + (size_t)NN * HH;                  // 64 KB
    float*    pden = T_T + (size_t)NN * HH;                // 64 KB
    uint32_t* gkey = (uint32_t*)(pden + (size_t)NN * HH);  // 16 B

    hipMemsetAsync(pden, 0, (size_t)NN * HH * sizeof(float) + 16, stream);
    cvt_inputs<<<(NN * FF / 4 + FF * FF / 4 + 255) / 256, 256, 0, stream>>>(x, W, xb, Wb);
    proj_fused<<<NN / ITILE, 256, 0, stream>>>(xb, Wb, a_src, a_dst, H_T, s, T_T, gkey);
    gat_main<<<dim3(NN / ITILE, NSLICE), 256, 0, stream>>>(adj, H_T, s, T_T, gkey, pden, part);
    finalize<<<NN, 256, 0, stream>>>(part, pden, out);
}